// Round 5
// baseline (397.843 us; speedup 1.0000x reference)
//
#include <hip/hip_runtime.h>
#include <cstdint>
#include <cstddef>

typedef unsigned short u16;
typedef __attribute__((ext_vector_type(8))) __bf16 bf16x8;
typedef __attribute__((ext_vector_type(4))) float floatx4;

#define Bz 8
#define Sz 1024
#define Dz 768
#define Hz 12
#define DHz 64

#define SB0 __builtin_amdgcn_sched_barrier(0)

__device__ __forceinline__ u16 f2b(float f) {
  unsigned u = __float_as_uint(f);
  return (u16)((u + 0x7fffu + ((u >> 16) & 1u)) >> 16);
}

// hardware RNE f32->bf16
__device__ __forceinline__ u16 f2b_hw(float f) {
  __bf16 h = (__bf16)f;
  return __builtin_bit_cast(u16, h);
}

__device__ __forceinline__ bf16x8 ld8(const u16* p) {
  union { uint4 u; bf16x8 b; } t;
  t.u = *reinterpret_cast<const uint4*>(p);
  return t.b;
}

// async global->LDS, 16B per lane; lds base must be wave-uniform (HW adds lane*16)
__device__ __forceinline__ void load_lds16(const u16* g, u16* l) {
  __builtin_amdgcn_global_load_lds(
      (const __attribute__((address_space(1))) unsigned int*)g,
      (__attribute__((address_space(3))) unsigned int*)l, 16, 0, 0);
}

// ---------------- conversions ----------------
__global__ __launch_bounds__(256) void cvt4(const float* __restrict__ src,
                                            u16* __restrict__ dst, int n4) {
  int i = blockIdx.x * 256 + threadIdx.x;
  if (i >= n4) return;
  float4 v = reinterpret_cast<const float4*>(src)[i];
  union { u16 s[4]; uint2 u; } t;
  t.s[0] = f2b(v.x); t.s[1] = f2b(v.y); t.s[2] = f2b(v.z); t.s[3] = f2b(v.w);
  reinterpret_cast<uint2*>(dst)[i] = t.u;
}

// transpose fp32 [K][N] -> bf16 [N][K]; for QKV pack s1/s2 select by column
__global__ __launch_bounds__(256)
void wtrans(const float* __restrict__ s0, const float* __restrict__ s1,
            const float* __restrict__ s2, u16* __restrict__ dst,
            int K, int N, int srcN) {
  __shared__ float T[32][33];
  const int tx = threadIdx.x & 31, ty = threadIdx.x >> 5;
  const int n0 = blockIdx.x * 32, k0 = blockIdx.y * 32;
  const int n = n0 + tx;
  const float* src = s0;
  int nn = n;
  if (s1 && n >= 1536) { src = s2; nn = n - 1536; }
  else if (s1 && n >= 768) { src = s1; nn = n - 768; }
#pragma unroll
  for (int i = 0; i < 4; ++i)
    T[ty + i * 8][tx] = src[(size_t)(k0 + ty + i * 8) * srcN + nn];
  __syncthreads();
#pragma unroll
  for (int i = 0; i < 4; ++i)
    dst[(size_t)(n0 + ty + i * 8) * K + k0 + tx] = f2b(T[tx][ty + i * 8]);
}

// ---------------- GEMM 128x128 (B^T input), proven 2-phase skeleton -------
// 3-buffer LDS, 2-deep prefetch, counted vmcnt(4), bank swizzle, XCD swizzle.
// Used for the N=768 GEMMs (O-proj, FFN2).  EPI 1: bias + resid -> fp32.
template <int EPI>
__global__ __launch_bounds__(256, 3)
void gemm_k(const u16* __restrict__ A, const u16* __restrict__ Bt,
            int M, int N, int K,
            const float* __restrict__ bias0, const float* __restrict__ resid,
            float* __restrict__ outF, u16* __restrict__ outB) {
  __shared__ __align__(16) u16 As[3][128 * 32];
  __shared__ __align__(16) u16 Bs[3][128 * 32];
  const int tid = threadIdx.x;
  const int lane = tid & 63, wave = tid >> 6;
  const int l15 = lane & 15, quad = lane >> 4;

  const int nx = gridDim.x;
  const int nwg = nx * gridDim.y;
  const int lin = blockIdx.y * nx + blockIdx.x;
  const int swz = (lin & 7) * (nwg >> 3) + (lin >> 3);
  const int bx = swz % nx, by = swz / nx;

  const int m0 = by * 128, n0 = bx * 128;
  const int wm = (wave >> 1) * 64, wn = (wave & 1) * 64;

  floatx4 acc[4][4];
#pragma unroll
  for (int i = 0; i < 4; ++i)
#pragma unroll
    for (int j = 0; j < 4; ++j) acc[i][j] = {0.f, 0.f, 0.f, 0.f};

  const int srow = lane >> 2;
  const int scol = (((lane & 3) ^ ((lane >> 3) & 3))) * 8;
  const u16* pA = A + (size_t)(m0 + wave * 32 + srow) * K + scol;
  const u16* pB = Bt + (size_t)(n0 + wave * 32 + srow) * K + scol;

#pragma unroll
  for (int t = 0; t < 2; ++t)
#pragma unroll
    for (int j = 0; j < 2; ++j) {
      load_lds16(pA + (size_t)(j * 16) * K + t * 32, &As[t][(wave * 2 + j) * 512]);
      load_lds16(pB + (size_t)(j * 16) * K + t * 32, &Bs[t][(wave * 2 + j) * 512]);
    }

  const int NIT = K >> 5;
  const int rsw = (l15 >> 1) & 3;
  int cur = 0;
  for (int i = 0; i < NIT; ++i) {
    if (i == NIT - 1) asm volatile("s_waitcnt vmcnt(0)" ::: "memory");
    else              asm volatile("s_waitcnt vmcnt(4)" ::: "memory");
    __builtin_amdgcn_s_barrier();
    bf16x8 af[4], bf[4];
#pragma unroll
    for (int ii = 0; ii < 4; ++ii)
      af[ii] = ld8(&As[cur][(wm + ii * 16 + l15) * 32 + (quad ^ rsw) * 8]);
#pragma unroll
    for (int j = 0; j < 4; ++j)
      bf[j] = ld8(&Bs[cur][(wn + j * 16 + l15) * 32 + (quad ^ rsw) * 8]);
    SB0;
    if (i + 2 < NIT) {
      const int k2 = (i + 2) << 5;
      int pf = cur + 2; if (pf >= 3) pf -= 3;
#pragma unroll
      for (int j = 0; j < 2; ++j) {
        load_lds16(pA + (size_t)(j * 16) * K + k2, &As[pf][(wave * 2 + j) * 512]);
        load_lds16(pB + (size_t)(j * 16) * K + k2, &Bs[pf][(wave * 2 + j) * 512]);
      }
    }
    SB0;
#pragma unroll
    for (int ii = 0; ii < 4; ++ii)
#pragma unroll
      for (int j = 0; j < 4; ++j)
        acc[ii][j] = __builtin_amdgcn_mfma_f32_16x16x32_bf16(af[ii], bf[j],
                                                             acc[ii][j], 0, 0, 0);
    cur += 1; if (cur == 3) cur = 0;
  }

#pragma unroll
  for (int i = 0; i < 4; ++i) {
    int mbase = m0 + wm + i * 16 + quad * 4;
#pragma unroll
    for (int j = 0; j < 4; ++j) {
      int n = n0 + wn + j * 16 + l15;
#pragma unroll
      for (int r = 0; r < 4; ++r) {
        int mm = mbase + r;
        float v = acc[i][j][r];
        if (EPI == 1) {
          v += bias0[n] + resid[(size_t)mm * N + n];
          outF[(size_t)mm * N + n] = v;
        } else {
          v += bias0[n];
          v = fmaxf(v, 0.f);
          outB[(size_t)mm * N + n] = f2b(v);
        }
      }
    }
  }
}

// ---------------- GEMM 256x256, faithful m201-style 4-phase/tile ----------
// R10: per K-tile (BK=64) 4 phases; each phase:
//   {ds_read quadrant frags (4 b128; +8 B b128 in phase 1)
//    issue ONE half-tile stage (2 global_load_lds)
//    [phase 4 only: counted vmcnt(6); last 2 tiles vmcnt(0)]
//    s_barrier; lgkmcnt(0); setprio(1); 16 MFMA; setprio(0); s_barrier}
// Half-tile flight map (derived; makes vmcnt(6) exact):
//   t.ph1 -> (t+1).A.h1 into buf c^1     (4th-newest at t.ph4 gate: confirmed)
//   t.ph2 -> (t+2).B.h0 into buf c       (B dead after t.ph1 lgkm+barrier)
//   t.ph3 -> (t+2).B.h1 into buf c
//   t.ph4 -> (t+2).A.h0 into buf c       (write lands >=300cy after q3 reads)
// At t.ph4: vmcnt(6) leaves exactly those 3 newest halves in flight; all of
// tile t+1 is older => resident.  8 waves (wr=wave>>2 M-half, wc=wave&3
// N-quarter), per-wave C=128x64, acc 128 VGPR.  T2 both-sides XOR swizzle,
// T5 setprio, bijective XCD remap.  LDS 128KB -> 1 block/CU (by design).
template <int EPI>
__global__ __launch_bounds__(512, 2)
void gemm8(const u16* __restrict__ A, const u16* __restrict__ Bt,
           int M, int N, int K,
           const float* __restrict__ bias0, const float* __restrict__ bias1,
           const float* __restrict__ bias2,
           u16* __restrict__ outB,
           u16* __restrict__ qO, u16* __restrict__ kO, u16* __restrict__ vtO) {
  __shared__ __align__(16) u16 As[2][256 * 64];
  __shared__ __align__(16) u16 Bs[2][256 * 64];
  const int tid = threadIdx.x;
  const int lane = tid & 63, wave = tid >> 6;
  const int l15 = lane & 15, quad = lane >> 4, l7 = lane & 7;
  const int wr = wave >> 2, wc = wave & 3;

  const int nx = gridDim.x;
  const int nwg = nx * gridDim.y;
  const int lin = blockIdx.y * nx + blockIdx.x;
  const int swz = (lin & 7) * (nwg >> 3) + (lin >> 3);
  const int bx = swz % nx, by = swz / nx;
  const int m0 = by * 256, n0 = bx * 256;

  floatx4 acc[8][4];
#pragma unroll
  for (int i = 0; i < 8; ++i)
#pragma unroll
    for (int j = 0; j < 4; ++j) acc[i][j] = {0.f, 0.f, 0.f, 0.f};

  // staging: one half-tile (128 rows x 64 cols) = 2 gloads/wave (8 rows each,
  // wave covers rows wave*16..+15).  Source chunk pre-swizzled (both-sides).
  const int schunk = (lane & 7) ^ ((lane >> 3) & 7);
  const u16* pA = A + (size_t)(m0 + wave * 16 + (lane >> 3)) * K + schunk * 8;
  const u16* pB = Bt + (size_t)(n0 + wave * 16 + (lane >> 3)) * K + schunk * 8;

  const int NT = K >> 6;

#define STG_A(buf, T, hf)                                                      \
  do {                                                                         \
    load_lds16(pA + (size_t)((hf) * 128) * K + (size_t)(T) * 64,               \
               &As[buf][(((hf) * 128) + wave * 16) * 64]);                     \
    load_lds16(pA + (size_t)((hf) * 128 + 8) * K + (size_t)(T) * 64,           \
               &As[buf][(((hf) * 128) + wave * 16 + 8) * 64]);                 \
  } while (0)
#define STG_B(buf, T, hf)                                                      \
  do {                                                                         \
    load_lds16(pB + (size_t)((hf) * 128) * K + (size_t)(T) * 64,               \
               &Bs[buf][(((hf) * 128) + wave * 16) * 64]);                     \
    load_lds16(pB + (size_t)((hf) * 128 + 8) * K + (size_t)(T) * 64,           \
               &Bs[buf][(((hf) * 128) + wave * 16 + 8) * 64]);                 \
  } while (0)

  // prologue: issue order = t0.B0,t0.B1,t0.A0,t0.A1,t1.B0,t1.B1,t1.A0
  STG_B(0, 0, 0); STG_B(0, 0, 1); STG_A(0, 0, 0); STG_A(0, 0, 1);
  STG_B(1, 1, 0); STG_B(1, 1, 1); STG_A(1, 1, 0);
  asm volatile("s_waitcnt vmcnt(6)" ::: "memory");   // tile0 resident
  __builtin_amdgcn_s_barrier();

  bf16x8 bfr[4][2];

  for (int t = 0; t < NT; ++t) {
    const int c = t & 1;
#pragma unroll
    for (int q = 0; q < 4; ++q) {
      bf16x8 af[2][2];
      if (q == 0) {
#pragma unroll
        for (int nj = 0; nj < 4; ++nj)
#pragma unroll
          for (int kk = 0; kk < 2; ++kk)
            bfr[nj][kk] = ld8(&Bs[c][(wc * 64 + nj * 16 + l15) * 64 +
                                     (((kk * 4 + quad) ^ l7) * 8)]);
      }
#pragma unroll
      for (int m2 = 0; m2 < 2; ++m2)
#pragma unroll
        for (int kk = 0; kk < 2; ++kk)
          af[m2][kk] = ld8(&As[c][(wr * 128 + (q * 2 + m2) * 16 + l15) * 64 +
                                  (((kk * 4 + quad) ^ l7) * 8)]);
      SB0;
      if (q == 0) {
        if (t + 1 < NT) STG_A(c ^ 1, t + 1, 1);
      } else if (q == 1) {
        if (t + 2 < NT) STG_B(c, t + 2, 0);
      } else if (q == 2) {
        if (t + 2 < NT) STG_B(c, t + 2, 1);
      } else {
        if (t + 2 < NT) STG_A(c, t + 2, 0);
      }
      SB0;
      if (q == 3) {
        if (t >= NT - 2) asm volatile("s_waitcnt vmcnt(0)" ::: "memory");
        else             asm volatile("s_waitcnt vmcnt(6)" ::: "memory");
      }
      __builtin_amdgcn_s_barrier();
      asm volatile("s_waitcnt lgkmcnt(0)" ::: "memory");
      SB0;
      __builtin_amdgcn_s_setprio(1);
#pragma unroll
      for (int m2 = 0; m2 < 2; ++m2)
#pragma unroll
        for (int nj = 0; nj < 4; ++nj)
#pragma unroll
          for (int kk = 0; kk < 2; ++kk)
            acc[q * 2 + m2][nj] = __builtin_amdgcn_mfma_f32_16x16x32_bf16(
                af[m2][kk], bfr[nj][kk], acc[q * 2 + m2][nj], 0, 0, 0);
      __builtin_amdgcn_s_setprio(0);
      SB0;
      __builtin_amdgcn_s_barrier();
    }
  }
#undef STG_A
#undef STG_B

#pragma unroll
  for (int mi = 0; mi < 8; ++mi) {
    int mbase = m0 + wr * 128 + mi * 16 + quad * 4;
#pragma unroll
    for (int nj = 0; nj < 4; ++nj) {
      int n = n0 + wc * 64 + nj * 16 + l15;
#pragma unroll
      for (int r = 0; r < 4; ++r) {
        int mm = mbase + r;
        float v = acc[mi][nj][r];
        if (EPI == 0) {
          if (n < 768) {
            v += bias0[n];
            qO[(size_t)mm * 768 + n] = f2b(v);
          } else if (n < 1536) {
            v += bias1[n - 768];
            kO[(size_t)mm * 768 + (n - 768)] = f2b(v);
          } else {
            int d = n - 1536;
            v += bias2[d];
            int hh = d >> 6, dh = d & 63;
            int bb = mm >> 10, ss = mm & 1023;
            vtO[((size_t)(bb * Hz + hh) * DHz + dh) * Sz + ss] = f2b(v);
          }
        } else {
          v += bias0[n];
          v = fmaxf(v, 0.f);
          outB[(size_t)mm * N + n] = f2b(v);
        }
      }
    }
  }
}

// ---------------- flash attention (double-buffered 64-key K/V tiles) -------
__global__ __launch_bounds__(256, 3)
void attn_k(const u16* __restrict__ q, const u16* __restrict__ kbuf,
            const u16* __restrict__ vt, const int* __restrict__ mask,
            u16* __restrict__ ctx) {
  __shared__ float addend[Sz];
  __shared__ __align__(16) u16 Ks[2][64 * 64];
  __shared__ __align__(16) u16 Vs[2][64 * 64];
  __shared__ __align__(16) u16 P[4][16][68];
  const int tid = threadIdx.x;
  const int wave = tid >> 6, lane = tid & 63;
  const int l15 = lane & 15, quad = lane >> 4;
  const int lin = blockIdx.y * 16 + blockIdx.x;
  const int swzid = (lin & 7) * 192 + (lin >> 3);
  const int bq = swzid & 15;
  const int bh = swzid >> 4;
  const int b = bh / Hz, h = bh - b * Hz;

  for (int s = tid; s < Sz; s += 256)
    addend[s] = mask[b * Sz + s] ? 0.f : -1e9f;

  const int qrow = bq * 64 + wave * 16 + l15;
  const u16* qp = q + (size_t)(b * Sz + qrow) * Dz + h * DHz;
  const bf16x8 fq0 = ld8(qp + quad * 8);
  const bf16x8 fq1 = ld8(qp + 32 + quad * 8);

  const int l7 = l15 & 7;
  const int s0q = quad ^ l7;

  const int srow = tid >> 3;
  const int spos = tid & 7;
  const int schunk = spos ^ (srow & 7);
  const u16* kg = kbuf + (size_t)(b * Sz + srow) * Dz + h * DHz + schunk * 8;
  const u16* vg = vt + (size_t)(b * Hz + h) * (DHz * Sz) + (size_t)srow * Sz +
                  schunk * 8;

  float m_l = -1e30f, l_l = 0.f;
  floatx4 o[4];
#pragma unroll
  for (int nt = 0; nt < 4; ++nt) o[nt] = {0.f, 0.f, 0.f, 0.f};

  load_lds16(kg, &Ks[0][wave * 512]);
  load_lds16(kg + (size_t)32 * Dz, &Ks[0][2048 + wave * 512]);
  load_lds16(vg, &Vs[0][wave * 512]);
  load_lds16(vg + (size_t)32 * Sz, &Vs[0][2048 + wave * 512]);

  for (int kt = 0; kt < 16; ++kt) {
    const int cur = kt & 1;
    asm volatile("s_waitcnt vmcnt(0)" ::: "memory");
    __builtin_amdgcn_s_barrier();
    bf16x8 fk0[4], fk1[4];
#pragma unroll
    for (int t = 0; t < 4; ++t) {
      const int krow = t * 16 + l15;
      fk0[t] = ld8(&Ks[cur][krow * 64 + s0q * 8]);
      fk1[t] = ld8(&Ks[cur][krow * 64 + (s0q ^ 4) * 8]);
    }
    SB0;
    if (kt + 1 < 16) {
      const size_t ko = (size_t)(kt + 1) * 64 * Dz;
      const int ve = (kt + 1) * 64;
      const int nb = cur ^ 1;
      load_lds16(kg + ko, &Ks[nb][wave * 512]);
      load_lds16(kg + ko + (size_t)32 * Dz, &Ks[nb][2048 + wave * 512]);
      load_lds16(vg + ve, &Vs[nb][wave * 512]);
      load_lds16(vg + ve + (size_t)32 * Sz, &Vs[nb][2048 + wave * 512]);
    }
    SB0;

    floatx4 z[4];
#pragma unroll
    for (int t = 0; t < 4; ++t) {
      floatx4 zz = {0.f, 0.f, 0.f, 0.f};
      zz = __builtin_amdgcn_mfma_f32_16x16x32_bf16(fk0[t], fq0, zz, 0, 0, 0);
      zz = __builtin_amdgcn_mfma_f32_16x16x32_bf16(fk1[t], fq1, zz, 0, 0, 0);
      const float4 ad =
          *reinterpret_cast<const float4*>(&addend[kt * 64 + t * 16 + quad * 4]);
      z[t][0] = zz[0] * 0.125f + ad.x;
      z[t][1] = zz[1] * 0.125f + ad.y;
      z[t][2] = zz[2] * 0.125f + ad.z;
      z[t][3] = zz[3] * 0.125f + ad.w;
    }
    float mx = fmaxf(fmaxf(z[0][0], z[0][1]), fmaxf(z[0][2], z[0][3]));
#pragma unroll
    for (int t = 1; t < 4; ++t)
      mx = fmaxf(mx, fmaxf(fmaxf(z[t][0], z[t][1]), fmaxf(z[t][2], z[t][3])));
    mx = fmaxf(mx, __shfl_xor(mx, 16, 64));
    mx = fmaxf(mx, __shfl_xor(mx, 32, 64));
    if (!__all(mx <= m_l + 8.f)) {
      const float nm = fmaxf(m_l, mx);
      const float alpha = __expf(m_l - nm);
      m_l = nm;
      l_l *= alpha;
      float av[4];
#pragma unroll
      for (int r = 0; r < 4; ++r) av[r] = __shfl(alpha, quad * 4 + r, 64);
#pragma unroll
      for (int nt = 0; nt < 4; ++nt)
#pragma unroll
        for (int r = 0; r < 4; ++r) o[nt][r] *= av[r];
    }
    float su = 0.f;
#pragma unroll
    for (int t = 0; t < 4; ++t) {
      union { u16 s[4]; uint2 u; } pk;
#pragma unroll
      for (int r = 0; r < 4; ++r) {
        float p = __expf(z[t][r] - m_l);
        su += p;
        pk.s[r] = f2b_hw(p);
      }
      *reinterpret_cast<uint2*>(&P[wave][l15][t * 16 + quad * 4]) = pk.u;
    }
    su += __shfl_xor(su, 16, 64);
    su += __shfl_xor(su, 32, 64);
    l_l += su;
    const bf16x8 ap0 = ld8(&P[wave][l15][quad * 8]);
    const bf16x8 ap1 = ld8(&P[wave][l15][32 + quad * 8]);
#pragma unroll
    for (int nt = 0; nt < 4; ++nt) {
      bf16x8 bv0 = ld8(&Vs[cur][(nt * 16 + l15) * 64 + ((quad ^ l7) * 8)]);
      bf16x8 bv1 = ld8(&Vs[cur][(nt * 16 + l15) * 64 + (((4 + quad) ^ l7) * 8)]);
      o[nt] = __builtin_amdgcn_mfma_f32_16x16x32_bf16(ap0, bv0, o[nt], 0, 0, 0);
      o[nt] = __builtin_amdgcn_mfma_f32_16x16x32_bf16(ap1, bv1, o[nt], 0, 0, 0);
    }
  }

  const float linv = 1.f / l_l;
  float lv[4];
#pragma unroll
  for (int r = 0; r < 4; ++r) lv[r] = __shfl(linv, quad * 4 + r, 64);
  const int qr = bq * 64 + wave * 16 + quad * 4;
#pragma unroll
  for (int nt = 0; nt < 4; ++nt)
#pragma unroll
    for (int r = 0; r < 4; ++r) {
      float v = o[nt][r] * lv[r];
      ctx[(size_t)(b * Sz + qr + r) * Dz + h * DHz + nt * 16 + l15] = f2b(v);
    }
}

// ---------------- layernorm (row = 768) ----------------
__global__ __launch_bounds__(256)
void ln_k(const float* __restrict__ in, const float* __restrict__ g,
          const float* __restrict__ be, float* __restrict__ outF,
          u16* __restrict__ outB) {
  const int row = blockIdx.x;
  const float* x = in + (size_t)row * Dz;
  const int tid = threadIdx.x;
  float v0 = x[tid], v1 = x[tid + 256], v2 = x[tid + 512];
  float s = v0 + v1 + v2;
  float s2 = v0 * v0 + v1 * v1 + v2 * v2;
#pragma unroll
  for (int off = 1; off < 64; off <<= 1) {
    s += __shfl_xor(s, off, 64);
    s2 += __shfl_xor(s2, off, 64);
  }
  __shared__ float red[8];
  int wave = tid >> 6, lane = tid & 63;
  if (lane == 0) { red[wave] = s; red[4 + wave] = s2; }
  __syncthreads();
  s = red[0] + red[1] + red[2] + red[3];
  s2 = red[4] + red[5] + red[6] + red[7];
  const float mu = s * (1.f / 768.f);
  const float rstd = rsqrtf(s2 * (1.f / 768.f) - mu * mu + 1e-5f);
  float vv[3] = {v0, v1, v2};
#pragma unroll
  for (int e = 0; e < 3; ++e) {
    int col = tid + e * 256;
    float y = (vv[e] - mu) * rstd * g[col] + be[col];
    outF[(size_t)row * Dz + col] = y;
    if (outB) outB[(size_t)row * Dz + col] = f2b(y);
  }
}

// ---------------- launch ----------------
extern "C" void kernel_launch(void* const* d_in, const int* in_sizes, int n_in,
                              void* d_out, int out_size, void* d_ws,
                              size_t ws_size, hipStream_t stream) {
  const float* x   = (const float*)d_in[0];
  const int*   msk = (const int*)d_in[1];
  const float* Wq  = (const float*)d_in[2];
  const float* bq  = (const float*)d_in[3];
  const float* Wk  = (const float*)d_in[4];
  const float* bk  = (const float*)d_in[5];
  const float* Wv  = (const float*)d_in[6];
  const float* bv  = (const float*)d_in[7];
  const float* Wo  = (const float*)d_in[8];
  const float* bo  = (const float*)d_in[9];
  const float* g1  = (const float*)d_in[10];
  const float* be1 = (const float*)d_in[11];
  const float* W1  = (const float*)d_in[12];
  const float* b1  = (const float*)d_in[13];
  const float* W2  = (const float*)d_in[14];
  const float* b2  = (const float*)d_in[15];
  const float* g2  = (const float*)d_in[16];
  const float* be2 = (const float*)d_in[17];
  float* out = (float*)d_out;

  char* ws = (char*)d_ws;
  u16*   xb    = (u16*)(ws + 0);
  u16*   wqkvb = (u16*)(ws + 12582912);   // [2304][768] bf16 (transposed)
  u16*   wob   = (u16*)(ws + 16121856);   // [768][768]
  u16*   w1b   = (u16*)(ws + 17301504);   // [1536][768]
  u16*   w2b   = (u16*)(ws + 19660800);   // [768][1536]
  u16*   qb    = (u16*)(ws + 22020096);
  u16*   kb    = (u16*)(ws + 34603008);
  u16*   vtb   = (u16*)(ws + 47185920);
  u16*   ctx   = (u16*)(ws + 59768832);
  float* att   = (float*)(ws + 72351744);
  float* hf    = (float*)(ws + 97517568);
  u16*   hb    = (u16*)(ws + 122683392);
  u16*   f1    = (u16*)(ws + 47185920);  // reuse vt+ctx (dead after O-proj)
  float* yy    = (float*)(ws + 22020096); // reuse q+k (dead after attention)

  cvt4<<<6291456 / 4 / 256, 256, 0, stream>>>(x, xb, 6291456 / 4);
  wtrans<<<dim3(2304 / 32, 768 / 32), 256, 0, stream>>>(Wq, Wk, Wv, wqkvb, 768,
                                                        2304, 768);
  wtrans<<<dim3(24, 24), 256, 0, stream>>>(Wo, nullptr, nullptr, wob, 768, 768,
                                           768);
  wtrans<<<dim3(48, 24), 256, 0, stream>>>(W1, nullptr, nullptr, w1b, 768, 1536,
                                           1536);
  wtrans<<<dim3(24, 48), 256, 0, stream>>>(W2, nullptr, nullptr, w2b, 1536, 768,
                                           768);

  // QKV: [8192x768] @ [768x2304] — 256x256 4-phase/tile
  gemm8<0><<<dim3(2304 / 256, 8192 / 256), 512, 0, stream>>>(
      xb, wqkvb, 8192, 2304, 768, bq, bk, bv, nullptr, qb, kb, vtb);
  // attention
  attn_k<<<dim3(Sz / 64, Bz * Hz), 256, 0, stream>>>(qb, kb, vtb, msk, ctx);
  // O-proj + residual x -> att (fp32) — 128x128 kernel
  gemm_k<1><<<dim3(768 / 128, 8192 / 128), 256, 0, stream>>>(
      ctx, wob, 8192, 768, 768, bo, x, att, nullptr);
  // LN1 -> hf (fp32) + hb (bf16)
  ln_k<<<8192, 256, 0, stream>>>(att, g1, be1, hf, hb);
  // FFN1 + relu -> f1 (bf16) — 256x256 4-phase/tile
  gemm8<2><<<dim3(1536 / 256, 8192 / 256), 512, 0, stream>>>(
      hb, w1b, 8192, 1536, 768, b1, nullptr, nullptr, f1, nullptr, nullptr,
      nullptr);
  // FFN2 + residual hf -> yy (fp32) — 128x128 kernel
  gemm_k<1><<<dim3(768 / 128, 8192 / 128), 256, 0, stream>>>(
      f1, w2b, 8192, 768, 1536, b2, hf, yy, nullptr);
  // LN2 -> out
  ln_k<<<8192, 256, 0, stream>>>(yy, g2, be2, out, nullptr);
}

// Round 7
// 368.516 us; speedup vs baseline: 1.0796x; 1.0796x over previous
//
#include <hip/hip_runtime.h>
#include <cstdint>
#include <cstddef>

typedef unsigned short u16;
typedef __attribute__((ext_vector_type(8))) __bf16 bf16x8;
typedef __attribute__((ext_vector_type(4))) float floatx4;

#define Bz 8
#define Sz 1024
#define Dz 768
#define Hz 12
#define DHz 64

#define SB0 __builtin_amdgcn_sched_barrier(0)

__device__ __forceinline__ u16 f2b(float f) {
  unsigned u = __float_as_uint(f);
  return (u16)((u + 0x7fffu + ((u >> 16) & 1u)) >> 16);
}

// hardware RNE f32->bf16
__device__ __forceinline__ u16 f2b_hw(float f) {
  __bf16 h = (__bf16)f;
  return __builtin_bit_cast(u16, h);
}

__device__ __forceinline__ bf16x8 ld8(const u16* p) {
  union { uint4 u; bf16x8 b; } t;
  t.u = *reinterpret_cast<const uint4*>(p);
  return t.b;
}

// async global->LDS, 16B per lane; lds base must be wave-uniform (HW adds lane*16)
__device__ __forceinline__ void load_lds16(const u16* g, u16* l) {
  __builtin_amdgcn_global_load_lds(
      (const __attribute__((address_space(1))) unsigned int*)g,
      (__attribute__((address_space(3))) unsigned int*)l, 16, 0, 0);
}

// ---------------- conversions ----------------
__global__ __launch_bounds__(256) void cvt4(const float* __restrict__ src,
                                            u16* __restrict__ dst, int n4) {
  int i = blockIdx.x * 256 + threadIdx.x;
  if (i >= n4) return;
  float4 v = reinterpret_cast<const float4*>(src)[i];
  union { u16 s[4]; uint2 u; } t;
  t.s[0] = f2b(v.x); t.s[1] = f2b(v.y); t.s[2] = f2b(v.z); t.s[3] = f2b(v.w);
  reinterpret_cast<uint2*>(dst)[i] = t.u;
}

// transpose fp32 [K][N] -> bf16 [N][K]; for QKV pack s1/s2 select by column
__global__ __launch_bounds__(256)
void wtrans(const float* __restrict__ s0, const float* __restrict__ s1,
            const float* __restrict__ s2, u16* __restrict__ dst,
            int K, int N, int srcN) {
  __shared__ float T[32][33];
  const int tx = threadIdx.x & 31, ty = threadIdx.x >> 5;
  const int n0 = blockIdx.x * 32, k0 = blockIdx.y * 32;
  const int n = n0 + tx;
  const float* src = s0;
  int nn = n;
  if (s1 && n >= 1536) { src = s2; nn = n - 1536; }
  else if (s1 && n >= 768) { src = s1; nn = n - 768; }
#pragma unroll
  for (int i = 0; i < 4; ++i)
    T[ty + i * 8][tx] = src[(size_t)(k0 + ty + i * 8) * srcN + nn];
  __syncthreads();
#pragma unroll
  for (int i = 0; i < 4; ++i)
    dst[(size_t)(n0 + ty + i * 8) * K + k0 + tx] = f2b(T[tx][ty + i * 8]);
}

// ---------------- GEMM 128x128 BK=32 (B^T input), proven 2-phase skeleton --
// 3-buffer LDS, 2-deep prefetch, counted vmcnt(4), bank swizzle, XCD swizzle.
// Used for O-proj (EPI1), FFN1 (EPI2), FFN2 (EPI1).
template <int EPI>
__global__ __launch_bounds__(256, 3)
void gemm_k(const u16* __restrict__ A, const u16* __restrict__ Bt,
            int M, int N, int K,
            const float* __restrict__ bias0, const float* __restrict__ resid,
            float* __restrict__ outF, u16* __restrict__ outB) {
  __shared__ __align__(16) u16 As[3][128 * 32];
  __shared__ __align__(16) u16 Bs[3][128 * 32];
  const int tid = threadIdx.x;
  const int lane = tid & 63, wave = tid >> 6;
  const int l15 = lane & 15, quad = lane >> 4;

  const int nx = gridDim.x;
  const int nwg = nx * gridDim.y;
  const int lin = blockIdx.y * nx + blockIdx.x;
  const int swz = (lin & 7) * (nwg >> 3) + (lin >> 3);
  const int bx = swz % nx, by = swz / nx;

  const int m0 = by * 128, n0 = bx * 128;
  const int wm = (wave >> 1) * 64, wn = (wave & 1) * 64;

  floatx4 acc[4][4];
#pragma unroll
  for (int i = 0; i < 4; ++i)
#pragma unroll
    for (int j = 0; j < 4; ++j) acc[i][j] = {0.f, 0.f, 0.f, 0.f};

  const int srow = lane >> 2;
  const int scol = (((lane & 3) ^ ((lane >> 3) & 3))) * 8;
  const u16* pA = A + (size_t)(m0 + wave * 32 + srow) * K + scol;
  const u16* pB = Bt + (size_t)(n0 + wave * 32 + srow) * K + scol;

#pragma unroll
  for (int t = 0; t < 2; ++t)
#pragma unroll
    for (int j = 0; j < 2; ++j) {
      load_lds16(pA + (size_t)(j * 16) * K + t * 32, &As[t][(wave * 2 + j) * 512]);
      load_lds16(pB + (size_t)(j * 16) * K + t * 32, &Bs[t][(wave * 2 + j) * 512]);
    }

  const int NIT = K >> 5;
  const int rsw = (l15 >> 1) & 3;
  int cur = 0;
  for (int i = 0; i < NIT; ++i) {
    if (i == NIT - 1) asm volatile("s_waitcnt vmcnt(0)" ::: "memory");
    else              asm volatile("s_waitcnt vmcnt(4)" ::: "memory");
    __builtin_amdgcn_s_barrier();
    bf16x8 af[4], bf[4];
#pragma unroll
    for (int ii = 0; ii < 4; ++ii)
      af[ii] = ld8(&As[cur][(wm + ii * 16 + l15) * 32 + (quad ^ rsw) * 8]);
#pragma unroll
    for (int j = 0; j < 4; ++j)
      bf[j] = ld8(&Bs[cur][(wn + j * 16 + l15) * 32 + (quad ^ rsw) * 8]);
    SB0;
    if (i + 2 < NIT) {
      const int k2 = (i + 2) << 5;
      int pf = cur + 2; if (pf >= 3) pf -= 3;
#pragma unroll
      for (int j = 0; j < 2; ++j) {
        load_lds16(pA + (size_t)(j * 16) * K + k2, &As[pf][(wave * 2 + j) * 512]);
        load_lds16(pB + (size_t)(j * 16) * K + k2, &Bs[pf][(wave * 2 + j) * 512]);
      }
    }
    SB0;
#pragma unroll
    for (int ii = 0; ii < 4; ++ii)
#pragma unroll
      for (int j = 0; j < 4; ++j)
        acc[ii][j] = __builtin_amdgcn_mfma_f32_16x16x32_bf16(af[ii], bf[j],
                                                             acc[ii][j], 0, 0, 0);
    cur += 1; if (cur == 3) cur = 0;
  }

#pragma unroll
  for (int i = 0; i < 4; ++i) {
    int mbase = m0 + wm + i * 16 + quad * 4;
#pragma unroll
    for (int j = 0; j < 4; ++j) {
      int n = n0 + wn + j * 16 + l15;
#pragma unroll
      for (int r = 0; r < 4; ++r) {
        int mm = mbase + r;
        float v = acc[i][j][r];
        if (EPI == 1) {
          v += bias0[n] + resid[(size_t)mm * N + n];
          outF[(size_t)mm * N + n] = v;
        } else {
          v += bias0[n];
          v = fmaxf(v, 0.f);
          outB[(size_t)mm * N + n] = f2b(v);
        }
      }
    }
  }
}

// ---------------- GEMM 128x128 BK=64 (QKV only) ---------------------------
// R11 (resubmit; R6 bench was an infra failure): same proven sync skeleton
// as gemm_k but K-step 64: 2 LDS buffers of [128][64] (64KB total -> same
// 2 blocks/CU as achieved today), 12 iterations instead of 24 ->
// per-iteration fixed cost (vmcnt drain + 4-wave barrier convergence) paid
// half as often; 32 MFMA + 16 ds_read per iteration.
// Swizzle: stage source chunk (lane&7)^(lane>>3), read chunk
// ((kk*4+quad)^l7) -> within each 8-lane LDS phase all 8 chunk slots distinct
// (conflict-free).  Prefetch below ds_reads (proven order), vmcnt(0) at top.
template <int EPI>
__global__ __launch_bounds__(256, 2)
void gemm64(const u16* __restrict__ A, const u16* __restrict__ Bt,
            int M, int N, int K,
            const float* __restrict__ bias0, const float* __restrict__ bias1,
            const float* __restrict__ bias2,
            u16* __restrict__ qO, u16* __restrict__ kO, u16* __restrict__ vtO) {
  __shared__ __align__(16) u16 As[2][128 * 64];
  __shared__ __align__(16) u16 Bs[2][128 * 64];
  const int tid = threadIdx.x;
  const int lane = tid & 63, wave = tid >> 6;
  const int l15 = lane & 15, quad = lane >> 4, l7 = lane & 7;

  const int nx = gridDim.x;
  const int nwg = nx * gridDim.y;
  const int lin = blockIdx.y * nx + blockIdx.x;
  const int swz = (lin & 7) * (nwg >> 3) + (lin >> 3);
  const int bx = swz % nx, by = swz / nx;

  const int m0 = by * 128, n0 = bx * 128;
  const int wm = (wave >> 1) * 64, wn = (wave & 1) * 64;

  floatx4 acc[4][4];
#pragma unroll
  for (int i = 0; i < 4; ++i)
#pragma unroll
    for (int j = 0; j < 4; ++j) acc[i][j] = {0.f, 0.f, 0.f, 0.f};

  // staging: per tensor per tile, each wave issues 4 loads covering rows
  // wave*32 + j*8 .. +7 (j=0..3); lane -> row +(lane>>3), chunk pre-swizzled.
  const int srow8 = lane >> 3;                 // 0..7
  const int schunk = (lane & 7) ^ srow8;       // both-sides XOR key = row&7
  const u16* pA = A + (size_t)(m0 + wave * 32 + srow8) * K + schunk * 8;
  const u16* pB = Bt + (size_t)(n0 + wave * 32 + srow8) * K + schunk * 8;

  // prologue: tile 0 into buf 0 (8 loads/thread)
#pragma unroll
  for (int j = 0; j < 4; ++j) {
    load_lds16(pA + (size_t)(j * 8) * K, &As[0][(wave * 32 + j * 8) * 64]);
    load_lds16(pB + (size_t)(j * 8) * K, &Bs[0][(wave * 32 + j * 8) * 64]);
  }

  const int NIT = K >> 6;
  for (int i = 0; i < NIT; ++i) {
    const int cur = i & 1;
    asm volatile("s_waitcnt vmcnt(0)" ::: "memory");
    __builtin_amdgcn_s_barrier();
    bf16x8 af[4][2], bf[4][2];
#pragma unroll
    for (int ii = 0; ii < 4; ++ii)
#pragma unroll
      for (int kk = 0; kk < 2; ++kk) {
        af[ii][kk] = ld8(&As[cur][(wm + ii * 16 + l15) * 64 +
                                  (((kk * 4 + quad) ^ l7) * 8)]);
        bf[ii][kk] = ld8(&Bs[cur][(wn + ii * 16 + l15) * 64 +
                                  (((kk * 4 + quad) ^ l7) * 8)]);
      }
    SB0;
    if (i + 1 < NIT) {
      const int k1 = (i + 1) << 6;
#pragma unroll
      for (int j = 0; j < 4; ++j) {
        load_lds16(pA + (size_t)(j * 8) * K + k1,
                   &As[cur ^ 1][(wave * 32 + j * 8) * 64]);
        load_lds16(pB + (size_t)(j * 8) * K + k1,
                   &Bs[cur ^ 1][(wave * 32 + j * 8) * 64]);
      }
    }
    SB0;
#pragma unroll
    for (int ii = 0; ii < 4; ++ii)
#pragma unroll
      for (int j = 0; j < 4; ++j)
#pragma unroll
        for (int kk = 0; kk < 2; ++kk)
          acc[ii][j] = __builtin_amdgcn_mfma_f32_16x16x32_bf16(
              af[ii][kk], bf[j][kk], acc[ii][j], 0, 0, 0);
  }

#pragma unroll
  for (int i = 0; i < 4; ++i) {
    int mbase = m0 + wm + i * 16 + quad * 4;
#pragma unroll
    for (int j = 0; j < 4; ++j) {
      int n = n0 + wn + j * 16 + l15;
#pragma unroll
      for (int r = 0; r < 4; ++r) {
        int mm = mbase + r;
        float v = acc[i][j][r];
        if (EPI == 0) {
          if (n < 768) {
            v += bias0[n];
            qO[(size_t)mm * 768 + n] = f2b(v);
          } else if (n < 1536) {
            v += bias1[n - 768];
            kO[(size_t)mm * 768 + (n - 768)] = f2b(v);
          } else {
            int d = n - 1536;
            v += bias2[d];
            int hh = d >> 6, dh = d & 63;
            int bb = mm >> 10, ss = mm & 1023;
            vtO[((size_t)(bb * Hz + hh) * DHz + dh) * Sz + ss] = f2b(v);
          }
        }
      }
    }
  }
}

// ---------------- flash attention (double-buffered 64-key K/V tiles) -------
__global__ __launch_bounds__(256, 3)
void attn_k(const u16* __restrict__ q, const u16* __restrict__ kbuf,
            const u16* __restrict__ vt, const int* __restrict__ mask,
            u16* __restrict__ ctx) {
  __shared__ float addend[Sz];
  __shared__ __align__(16) u16 Ks[2][64 * 64];
  __shared__ __align__(16) u16 Vs[2][64 * 64];
  __shared__ __align__(16) u16 P[4][16][68];
  const int tid = threadIdx.x;
  const int wave = tid >> 6, lane = tid & 63;
  const int l15 = lane & 15, quad = lane >> 4;
  const int lin = blockIdx.y * 16 + blockIdx.x;
  const int swzid = (lin & 7) * 192 + (lin >> 3);
  const int bq = swzid & 15;
  const int bh = swzid >> 4;
  const int b = bh / Hz, h = bh - b * Hz;

  for (int s = tid; s < Sz; s += 256)
    addend[s] = mask[b * Sz + s] ? 0.f : -1e9f;

  const int qrow = bq * 64 + wave * 16 + l15;
  const u16* qp = q + (size_t)(b * Sz + qrow) * Dz + h * DHz;
  const bf16x8 fq0 = ld8(qp + quad * 8);
  const bf16x8 fq1 = ld8(qp + 32 + quad * 8);

  const int l7 = l15 & 7;
  const int s0q = quad ^ l7;

  const int srow = tid >> 3;
  const int spos = tid & 7;
  const int schunk = spos ^ (srow & 7);
  const u16* kg = kbuf + (size_t)(b * Sz + srow) * Dz + h * DHz + schunk * 8;
  const u16* vg = vt + (size_t)(b * Hz + h) * (DHz * Sz) + (size_t)srow * Sz +
                  schunk * 8;

  float m_l = -1e30f, l_l = 0.f;
  floatx4 o[4];
#pragma unroll
  for (int nt = 0; nt < 4; ++nt) o[nt] = {0.f, 0.f, 0.f, 0.f};

  load_lds16(kg, &Ks[0][wave * 512]);
  load_lds16(kg + (size_t)32 * Dz, &Ks[0][2048 + wave * 512]);
  load_lds16(vg, &Vs[0][wave * 512]);
  load_lds16(vg + (size_t)32 * Sz, &Vs[0][2048 + wave * 512]);

  for (int kt = 0; kt < 16; ++kt) {
    const int cur = kt & 1;
    asm volatile("s_waitcnt vmcnt(0)" ::: "memory");
    __builtin_amdgcn_s_barrier();
    bf16x8 fk0[4], fk1[4];
#pragma unroll
    for (int t = 0; t < 4; ++t) {
      const int krow = t * 16 + l15;
      fk0[t] = ld8(&Ks[cur][krow * 64 + s0q * 8]);
      fk1[t] = ld8(&Ks[cur][krow * 64 + (s0q ^ 4) * 8]);
    }
    SB0;
    if (kt + 1 < 16) {
      const size_t ko = (size_t)(kt + 1) * 64 * Dz;
      const int ve = (kt + 1) * 64;
      const int nb = cur ^ 1;
      load_lds16(kg + ko, &Ks[nb][wave * 512]);
      load_lds16(kg + ko + (size_t)32 * Dz, &Ks[nb][2048 + wave * 512]);
      load_lds16(vg + ve, &Vs[nb][wave * 512]);
      load_lds16(vg + ve + (size_t)32 * Sz, &Vs[nb][2048 + wave * 512]);
    }
    SB0;

    floatx4 z[4];
#pragma unroll
    for (int t = 0; t < 4; ++t) {
      floatx4 zz = {0.f, 0.f, 0.f, 0.f};
      zz = __builtin_amdgcn_mfma_f32_16x16x32_bf16(fk0[t], fq0, zz, 0, 0, 0);
      zz = __builtin_amdgcn_mfma_f32_16x16x32_bf16(fk1[t], fq1, zz, 0, 0, 0);
      const float4 ad =
          *reinterpret_cast<const float4*>(&addend[kt * 64 + t * 16 + quad * 4]);
      z[t][0] = zz[0] * 0.125f + ad.x;
      z[t][1] = zz[1] * 0.125f + ad.y;
      z[t][2] = zz[2] * 0.125f + ad.z;
      z[t][3] = zz[3] * 0.125f + ad.w;
    }
    float mx = fmaxf(fmaxf(z[0][0], z[0][1]), fmaxf(z[0][2], z[0][3]));
#pragma unroll
    for (int t = 1; t < 4; ++t)
      mx = fmaxf(mx, fmaxf(fmaxf(z[t][0], z[t][1]), fmaxf(z[t][2], z[t][3])));
    mx = fmaxf(mx, __shfl_xor(mx, 16, 64));
    mx = fmaxf(mx, __shfl_xor(mx, 32, 64));
    if (!__all(mx <= m_l + 8.f)) {
      const float nm = fmaxf(m_l, mx);
      const float alpha = __expf(m_l - nm);
      m_l = nm;
      l_l *= alpha;
      float av[4];
#pragma unroll
      for (int r = 0; r < 4; ++r) av[r] = __shfl(alpha, quad * 4 + r, 64);
#pragma unroll
      for (int nt = 0; nt < 4; ++nt)
#pragma unroll
        for (int r = 0; r < 4; ++r) o[nt][r] *= av[r];
    }
    float su = 0.f;
#pragma unroll
    for (int t = 0; t < 4; ++t) {
      union { u16 s[4]; uint2 u; } pk;
#pragma unroll
      for (int r = 0; r < 4; ++r) {
        float p = __expf(z[t][r] - m_l);
        su += p;
        pk.s[r] = f2b_hw(p);
      }
      *reinterpret_cast<uint2*>(&P[wave][l15][t * 16 + quad * 4]) = pk.u;
    }
    su += __shfl_xor(su, 16, 64);
    su += __shfl_xor(su, 32, 64);
    l_l += su;
    const bf16x8 ap0 = ld8(&P[wave][l15][quad * 8]);
    const bf16x8 ap1 = ld8(&P[wave][l15][32 + quad * 8]);
#pragma unroll
    for (int nt = 0; nt < 4; ++nt) {
      bf16x8 bv0 = ld8(&Vs[cur][(nt * 16 + l15) * 64 + ((quad ^ l7) * 8)]);
      bf16x8 bv1 = ld8(&Vs[cur][(nt * 16 + l15) * 64 + (((4 + quad) ^ l7) * 8)]);
      o[nt] = __builtin_amdgcn_mfma_f32_16x16x32_bf16(ap0, bv0, o[nt], 0, 0, 0);
      o[nt] = __builtin_amdgcn_mfma_f32_16x16x32_bf16(ap1, bv1, o[nt], 0, 0, 0);
    }
  }

  const float linv = 1.f / l_l;
  float lv[4];
#pragma unroll
  for (int r = 0; r < 4; ++r) lv[r] = __shfl(linv, quad * 4 + r, 64);
  const int qr = bq * 64 + wave * 16 + quad * 4;
#pragma unroll
  for (int nt = 0; nt < 4; ++nt)
#pragma unroll
    for (int r = 0; r < 4; ++r) {
      float v = o[nt][r] * lv[r];
      ctx[(size_t)(b * Sz + qr + r) * Dz + h * DHz + nt * 16 + l15] = f2b(v);
    }
}

// ---------------- layernorm (row = 768) ----------------
__global__ __launch_bounds__(256)
void ln_k(const float* __restrict__ in, const float* __restrict__ g,
          const float* __restrict__ be, float* __restrict__ outF,
          u16* __restrict__ outB) {
  const int row = blockIdx.x;
  const float* x = in + (size_t)row * Dz;
  const int tid = threadIdx.x;
  float v0 = x[tid], v1 = x[tid + 256], v2 = x[tid + 512];
  float s = v0 + v1 + v2;
  float s2 = v0 * v0 + v1 * v1 + v2 * v2;
#pragma unroll
  for (int off = 1; off < 64; off <<= 1) {
    s += __shfl_xor(s, off, 64);
    s2 += __shfl_xor(s2, off, 64);
  }
  __shared__ float red[8];
  int wave = tid >> 6, lane = tid & 63;
  if (lane == 0) { red[wave] = s; red[4 + wave] = s2; }
  __syncthreads();
  s = red[0] + red[1] + red[2] + red[3];
  s2 = red[4] + red[5] + red[6] + red[7];
  const float mu = s * (1.f / 768.f);
  const float rstd = rsqrtf(s2 * (1.f / 768.f) - mu * mu + 1e-5f);
  float vv[3] = {v0, v1, v2};
#pragma unroll
  for (int e = 0; e < 3; ++e) {
    int col = tid + e * 256;
    float y = (vv[e] - mu) * rstd * g[col] + be[col];
    outF[(size_t)row * Dz + col] = y;
    if (outB) outB[(size_t)row * Dz + col] = f2b(y);
  }
}

// ---------------- launch ----------------
extern "C" void kernel_launch(void* const* d_in, const int* in_sizes, int n_in,
                              void* d_out, int out_size, void* d_ws,
                              size_t ws_size, hipStream_t stream) {
  const float* x   = (const float*)d_in[0];
  const int*   msk = (const int*)d_in[1];
  const float* Wq  = (const float*)d_in[2];
  const float* bq  = (const float*)d_in[3];
  const float* Wk  = (const float*)d_in[4];
  const float* bk  = (const float*)d_in[5];
  const float* Wv  = (const float*)d_in[6];
  const float* bv  = (const float*)d_in[7];
  const float* Wo  = (const float*)d_in[8];
  const float* bo  = (const float*)d_in[9];
  const float* g1  = (const float*)d_in[10];
  const float* be1 = (const float*)d_in[11];
  const float* W1  = (const float*)d_in[12];
  const float* b1  = (const float*)d_in[13];
  const float* W2  = (const float*)d_in[14];
  const float* b2  = (const float*)d_in[15];
  const float* g2  = (const float*)d_in[16];
  const float* be2 = (const float*)d_in[17];
  float* out = (float*)d_out;

  char* ws = (char*)d_ws;
  u16*   xb    = (u16*)(ws + 0);
  u16*   wqkvb = (u16*)(ws + 12582912);   // [2304][768] bf16 (transposed)
  u16*   wob   = (u16*)(ws + 16121856);   // [768][768]
  u16*   w1b   = (u16*)(ws + 17301504);   // [1536][768]
  u16*   w2b   = (u16*)(ws + 19660800);   // [768][1536]
  u16*   qb    = (u16*)(ws + 22020096);
  u16*   kb    = (u16*)(ws + 34603008);
  u16*   vtb   = (u16*)(ws + 47185920);
  u16*   ctx   = (u16*)(ws + 59768832);
  float* att   = (float*)(ws + 72351744);
  float* hf    = (float*)(ws + 97517568);
  u16*   hb    = (u16*)(ws + 122683392);
  u16*   f1    = (u16*)(ws + 47185920);  // reuse vt+ctx (dead after O-proj)
  float* yy    = (float*)(ws + 22020096); // reuse q+k (dead after attention)

  cvt4<<<6291456 / 4 / 256, 256, 0, stream>>>(x, xb, 6291456 / 4);
  wtrans<<<dim3(2304 / 32, 768 / 32), 256, 0, stream>>>(Wq, Wk, Wv, wqkvb, 768,
                                                        2304, 768);
  wtrans<<<dim3(24, 24), 256, 0, stream>>>(Wo, nullptr, nullptr, wob, 768, 768,
                                           768);
  wtrans<<<dim3(48, 24), 256, 0, stream>>>(W1, nullptr, nullptr, w1b, 768, 1536,
                                           1536);
  wtrans<<<dim3(24, 48), 256, 0, stream>>>(W2, nullptr, nullptr, w2b, 1536, 768,
                                           768);

  // QKV: [8192x768] @ [768x2304] — 128x128 BK=64 (R11 experiment)
  gemm64<0><<<dim3(2304 / 128, 8192 / 128), 256, 0, stream>>>(
      xb, wqkvb, 8192, 2304, 768, bq, bk, bv, qb, kb, vtb);
  // attention
  attn_k<<<dim3(Sz / 64, Bz * Hz), 256, 0, stream>>>(qb, kb, vtb, msk, ctx);
  // O-proj + residual x -> att (fp32) — proven BK=32 kernel
  gemm_k<1><<<dim3(768 / 128, 8192 / 128), 256, 0, stream>>>(
      ctx, wob, 8192, 768, 768, bo, x, att, nullptr);
  // LN1 -> hf (fp32) + hb (bf16)
  ln_k<<<8192, 256, 0, stream>>>(att, g1, be1, hf, hb);
  // FFN1 + relu -> f1 (bf16) — proven BK=32 kernel
  gemm_k<2><<<dim3(1536 / 128, 8192 / 128), 256, 0, stream>>>(
      hb, w1b, 8192, 1536, 768, b1, nullptr, nullptr, f1);
  // FFN2 + residual hf -> yy (fp32) — proven BK=32 kernel
  gemm_k<1><<<dim3(768 / 128, 8192 / 128), 256, 0, stream>>>(
      f1, w2b, 8192, 768, 1536, b2, hf, yy, nullptr);
  // LN2 -> out
  ln_k<<<8192, 256, 0, stream>>>(yy, g2, be2, out, nullptr);
}

// Round 8
// 359.836 us; speedup vs baseline: 1.1056x; 1.0241x over previous
//
#include <hip/hip_runtime.h>
#include <cstdint>
#include <cstddef>

typedef unsigned short u16;
typedef __attribute__((ext_vector_type(8))) __bf16 bf16x8;
typedef __attribute__((ext_vector_type(4))) float floatx4;

#define Bz 8
#define Sz 1024
#define Dz 768
#define Hz 12
#define DHz 64

#define SB0 __builtin_amdgcn_sched_barrier(0)

__device__ __forceinline__ u16 f2b(float f) {
  unsigned u = __float_as_uint(f);
  return (u16)((u + 0x7fffu + ((u >> 16) & 1u)) >> 16);
}

// hardware RNE f32->bf16
__device__ __forceinline__ u16 f2b_hw(float f) {
  __bf16 h = (__bf16)f;
  return __builtin_bit_cast(u16, h);
}

__device__ __forceinline__ bf16x8 ld8(const u16* p) {
  union { uint4 u; bf16x8 b; } t;
  t.u = *reinterpret_cast<const uint4*>(p);
  return t.b;
}

// async global->LDS, 16B per lane; lds base must be wave-uniform (HW adds lane*16)
__device__ __forceinline__ void load_lds16(const u16* g, u16* l) {
  __builtin_amdgcn_global_load_lds(
      (const __attribute__((address_space(1))) unsigned int*)g,
      (__attribute__((address_space(3))) unsigned int*)l, 16, 0, 0);
}

// ---------------- conversions ----------------
__global__ __launch_bounds__(256) void cvt4(const float* __restrict__ src,
                                            u16* __restrict__ dst, int n4) {
  int i = blockIdx.x * 256 + threadIdx.x;
  if (i >= n4) return;
  float4 v = reinterpret_cast<const float4*>(src)[i];
  union { u16 s[4]; uint2 u; } t;
  t.s[0] = f2b(v.x); t.s[1] = f2b(v.y); t.s[2] = f2b(v.z); t.s[3] = f2b(v.w);
  reinterpret_cast<uint2*>(dst)[i] = t.u;
}

// transpose fp32 [K][N] -> bf16 [N][K]; for QKV pack s1/s2 select by column
__global__ __launch_bounds__(256)
void wtrans(const float* __restrict__ s0, const float* __restrict__ s1,
            const float* __restrict__ s2, u16* __restrict__ dst,
            int K, int N, int srcN) {
  __shared__ float T[32][33];
  const int tx = threadIdx.x & 31, ty = threadIdx.x >> 5;
  const int n0 = blockIdx.x * 32, k0 = blockIdx.y * 32;
  const int n = n0 + tx;
  const float* src = s0;
  int nn = n;
  if (s1 && n >= 1536) { src = s2; nn = n - 1536; }
  else if (s1 && n >= 768) { src = s1; nn = n - 768; }
#pragma unroll
  for (int i = 0; i < 4; ++i)
    T[ty + i * 8][tx] = src[(size_t)(k0 + ty + i * 8) * srcN + nn];
  __syncthreads();
#pragma unroll
  for (int i = 0; i < 4; ++i)
    dst[(size_t)(n0 + ty + i * 8) * K + k0 + tx] = f2b(T[tx][ty + i * 8]);
}

// ---------------- GEMM (B^T input): C = A(MxK) * Bt(NxK)^T + epilogue ------
// R2-champion config: 3-buffer LDS, 2-tiles-ahead prefetch, counted vmcnt(4)
// at loop head (vmcnt(0) last iter), prefetch BELOW frag ds_reads, bank
// swizzle both-sides, bijective XCD remap.  Empirically the best structure
// for these shapes (K=768/1536, N<=2304): BN=256, 8-phase 256^2, and BK=64
// all measured worse (R3-R7).
// EPI 0: QKV scatter; EPI 1: bias0 + resid (fp32) -> outF; EPI 2: bias0+relu->outB
template <int EPI>
__global__ __launch_bounds__(256, 3)
void gemm_k(const u16* __restrict__ A, const u16* __restrict__ Bt,
            int M, int N, int K,
            const float* __restrict__ bias0, const float* __restrict__ bias1,
            const float* __restrict__ bias2, const float* __restrict__ resid,
            float* __restrict__ outF, u16* __restrict__ outB,
            u16* __restrict__ qO, u16* __restrict__ kO, u16* __restrict__ vtO) {
  __shared__ __align__(16) u16 As[3][128 * 32];
  __shared__ __align__(16) u16 Bs[3][128 * 32];
  const int tid = threadIdx.x;
  const int lane = tid & 63, wave = tid >> 6;
  const int l15 = lane & 15, quad = lane >> 4;

  // bijective XCD-aware remap of the linear workgroup id
  const int nx = gridDim.x;
  const int nwg = nx * gridDim.y;
  const int lin = blockIdx.y * nx + blockIdx.x;
  const int swz = (lin & 7) * (nwg >> 3) + (lin >> 3);
  const int bx = swz % nx, by = swz / nx;

  const int m0 = by * 128, n0 = bx * 128;
  const int wm = (wave >> 1) * 64, wn = (wave & 1) * 64;

  floatx4 acc[4][4];
#pragma unroll
  for (int i = 0; i < 4; ++i)
#pragma unroll
    for (int j = 0; j < 4; ++j) acc[i][j] = {0.f, 0.f, 0.f, 0.f};

  const int srow = lane >> 2;
  const int scol = (((lane & 3) ^ ((lane >> 3) & 3))) * 8;
  const u16* pA = A + (size_t)(m0 + wave * 32 + srow) * K + scol;
  const u16* pB = Bt + (size_t)(n0 + wave * 32 + srow) * K + scol;

  // prologue: stage tiles 0 and 1 into bufs 0,1
#pragma unroll
  for (int t = 0; t < 2; ++t)
#pragma unroll
    for (int j = 0; j < 2; ++j) {
      load_lds16(pA + (size_t)(j * 16) * K + t * 32, &As[t][(wave * 2 + j) * 512]);
      load_lds16(pB + (size_t)(j * 16) * K + t * 32, &Bs[t][(wave * 2 + j) * 512]);
    }

  const int NIT = K >> 5;
  const int rsw = (l15 >> 1) & 3;      // read-side bank swizzle key
  int cur = 0;
  for (int i = 0; i < NIT; ++i) {
    if (i == NIT - 1) asm volatile("s_waitcnt vmcnt(0)" ::: "memory");
    else              asm volatile("s_waitcnt vmcnt(4)" ::: "memory");
    __builtin_amdgcn_s_barrier();
    bf16x8 af[4], bf[4];
#pragma unroll
    for (int ii = 0; ii < 4; ++ii)
      af[ii] = ld8(&As[cur][(wm + ii * 16 + l15) * 32 + (quad ^ rsw) * 8]);
#pragma unroll
    for (int j = 0; j < 4; ++j)
      bf[j] = ld8(&Bs[cur][(wn + j * 16 + l15) * 32 + (quad ^ rsw) * 8]);
    SB0;
    if (i + 2 < NIT) {
      const int k2 = (i + 2) << 5;
      int pf = cur + 2; if (pf >= 3) pf -= 3;
#pragma unroll
      for (int j = 0; j < 2; ++j) {
        load_lds16(pA + (size_t)(j * 16) * K + k2, &As[pf][(wave * 2 + j) * 512]);
        load_lds16(pB + (size_t)(j * 16) * K + k2, &Bs[pf][(wave * 2 + j) * 512]);
      }
    }
    SB0;
#pragma unroll
    for (int ii = 0; ii < 4; ++ii)
#pragma unroll
      for (int j = 0; j < 4; ++j)
        acc[ii][j] = __builtin_amdgcn_mfma_f32_16x16x32_bf16(af[ii], bf[j],
                                                             acc[ii][j], 0, 0, 0);
    cur += 1; if (cur == 3) cur = 0;
  }

#pragma unroll
  for (int i = 0; i < 4; ++i) {
    int mbase = m0 + wm + i * 16 + quad * 4;
#pragma unroll
    for (int j = 0; j < 4; ++j) {
      int n = n0 + wn + j * 16 + l15;
#pragma unroll
      for (int r = 0; r < 4; ++r) {
        int mm = mbase + r;
        float v = acc[i][j][r];
        if (EPI == 0) {
          if (n < 768) {
            v += bias0[n];
            qO[(size_t)mm * 768 + n] = f2b(v);
          } else if (n < 1536) {
            v += bias1[n - 768];
            kO[(size_t)mm * 768 + (n - 768)] = f2b(v);
          } else {
            int d = n - 1536;
            v += bias2[d];
            int hh = d >> 6, dh = d & 63;
            int bb = mm >> 10, ss = mm & 1023;
            vtO[((size_t)(bb * Hz + hh) * DHz + dh) * Sz + ss] = f2b(v);
          }
        } else if (EPI == 1) {
          v += bias0[n] + resid[(size_t)mm * N + n];
          outF[(size_t)mm * N + n] = v;
        } else {
          v += bias0[n];
          v = fmaxf(v, 0.f);
          outB[(size_t)mm * N + n] = f2b(v);
        }
      }
    }
  }
}

// ---------------- flash attention (double-buffered 64-key K/V tiles) -------
// R2 structure + T5 setprio around the MFMA clusters (m191: waves within a
// tile run softmax/PV unsynchronized -> scheduler has roles to arbitrate).
__global__ __launch_bounds__(256, 3)
void attn_k(const u16* __restrict__ q, const u16* __restrict__ kbuf,
            const u16* __restrict__ vt, const int* __restrict__ mask,
            u16* __restrict__ ctx) {
  __shared__ float addend[Sz];
  __shared__ __align__(16) u16 Ks[2][64 * 64];
  __shared__ __align__(16) u16 Vs[2][64 * 64];
  __shared__ __align__(16) u16 P[4][16][68];
  const int tid = threadIdx.x;
  const int wave = tid >> 6, lane = tid & 63;
  const int l15 = lane & 15, quad = lane >> 4;
  // bijective XCD swizzle: grid (16,96) = 1536 wgs; 192 consecutive per XCD
  const int lin = blockIdx.y * 16 + blockIdx.x;
  const int swzid = (lin & 7) * 192 + (lin >> 3);
  const int bq = swzid & 15;
  const int bh = swzid >> 4;
  const int b = bh / Hz, h = bh - b * Hz;

  for (int s = tid; s < Sz; s += 256)
    addend[s] = mask[b * Sz + s] ? 0.f : -1e9f;

  const int qrow = bq * 64 + wave * 16 + l15;
  const u16* qp = q + (size_t)(b * Sz + qrow) * Dz + h * DHz;
  const bf16x8 fq0 = ld8(qp + quad * 8);
  const bf16x8 fq1 = ld8(qp + 32 + quad * 8);

  const int l7 = l15 & 7;
  const int s0q = quad ^ l7;

  const int srow = tid >> 3;
  const int spos = tid & 7;
  const int schunk = spos ^ (srow & 7);
  const u16* kg = kbuf + (size_t)(b * Sz + srow) * Dz + h * DHz + schunk * 8;
  const u16* vg = vt + (size_t)(b * Hz + h) * (DHz * Sz) + (size_t)srow * Sz +
                  schunk * 8;

  float m_l = -1e30f, l_l = 0.f;
  floatx4 o[4];
#pragma unroll
  for (int nt = 0; nt < 4; ++nt) o[nt] = {0.f, 0.f, 0.f, 0.f};

  // prologue: stage tile 0 into buf 0 (K j0, K j1, V j0, V j1)
  load_lds16(kg, &Ks[0][wave * 512]);
  load_lds16(kg + (size_t)32 * Dz, &Ks[0][2048 + wave * 512]);
  load_lds16(vg, &Vs[0][wave * 512]);
  load_lds16(vg + (size_t)32 * Sz, &Vs[0][2048 + wave * 512]);

  for (int kt = 0; kt < 16; ++kt) {
    const int cur = kt & 1;
    asm volatile("s_waitcnt vmcnt(0)" ::: "memory");
    __builtin_amdgcn_s_barrier();
    bf16x8 fk0[4], fk1[4];
#pragma unroll
    for (int t = 0; t < 4; ++t) {
      const int krow = t * 16 + l15;
      fk0[t] = ld8(&Ks[cur][krow * 64 + s0q * 8]);
      fk1[t] = ld8(&Ks[cur][krow * 64 + (s0q ^ 4) * 8]);
    }
    SB0;
    if (kt + 1 < 16) {
      const size_t ko = (size_t)(kt + 1) * 64 * Dz;
      const int ve = (kt + 1) * 64;
      const int nb = cur ^ 1;
      load_lds16(kg + ko, &Ks[nb][wave * 512]);
      load_lds16(kg + ko + (size_t)32 * Dz, &Ks[nb][2048 + wave * 512]);
      load_lds16(vg + ve, &Vs[nb][wave * 512]);
      load_lds16(vg + ve + (size_t)32 * Sz, &Vs[nb][2048 + wave * 512]);
    }
    SB0;

    // QK^T (rows = keys, cols = q)
    floatx4 z[4];
    __builtin_amdgcn_s_setprio(1);
#pragma unroll
    for (int t = 0; t < 4; ++t) {
      floatx4 zz = {0.f, 0.f, 0.f, 0.f};
      zz = __builtin_amdgcn_mfma_f32_16x16x32_bf16(fk0[t], fq0, zz, 0, 0, 0);
      zz = __builtin_amdgcn_mfma_f32_16x16x32_bf16(fk1[t], fq1, zz, 0, 0, 0);
      const float4 ad =
          *reinterpret_cast<const float4*>(&addend[kt * 64 + t * 16 + quad * 4]);
      z[t][0] = zz[0] * 0.125f + ad.x;
      z[t][1] = zz[1] * 0.125f + ad.y;
      z[t][2] = zz[2] * 0.125f + ad.z;
      z[t][3] = zz[3] * 0.125f + ad.w;
    }
    __builtin_amdgcn_s_setprio(0);
    float mx = fmaxf(fmaxf(z[0][0], z[0][1]), fmaxf(z[0][2], z[0][3]));
#pragma unroll
    for (int t = 1; t < 4; ++t)
      mx = fmaxf(mx, fmaxf(fmaxf(z[t][0], z[t][1]), fmaxf(z[t][2], z[t][3])));
    mx = fmaxf(mx, __shfl_xor(mx, 16, 64));
    mx = fmaxf(mx, __shfl_xor(mx, 32, 64));
    // T13 defer-max: rescale only when some row's max grew past m+8
    if (!__all(mx <= m_l + 8.f)) {
      const float nm = fmaxf(m_l, mx);
      const float alpha = __expf(m_l - nm);
      m_l = nm;
      l_l *= alpha;
      float av[4];
#pragma unroll
      for (int r = 0; r < 4; ++r) av[r] = __shfl(alpha, quad * 4 + r, 64);
#pragma unroll
      for (int nt = 0; nt < 4; ++nt)
#pragma unroll
        for (int r = 0; r < 4; ++r) o[nt][r] *= av[r];
    }
    float su = 0.f;
#pragma unroll
    for (int t = 0; t < 4; ++t) {
      union { u16 s[4]; uint2 u; } pk;
#pragma unroll
      for (int r = 0; r < 4; ++r) {
        float p = __expf(z[t][r] - m_l);
        su += p;
        pk.s[r] = f2b_hw(p);
      }
      *reinterpret_cast<uint2*>(&P[wave][l15][t * 16 + quad * 4]) = pk.u;
    }
    su += __shfl_xor(su, 16, 64);
    su += __shfl_xor(su, 32, 64);
    l_l += su;
    // PV: P as A-operand (rows = q), V^T as B-operand (cols = dh)
    const bf16x8 ap0 = ld8(&P[wave][l15][quad * 8]);
    const bf16x8 ap1 = ld8(&P[wave][l15][32 + quad * 8]);
    __builtin_amdgcn_s_setprio(1);
#pragma unroll
    for (int nt = 0; nt < 4; ++nt) {
      bf16x8 bv0 = ld8(&Vs[cur][(nt * 16 + l15) * 64 + ((quad ^ l7) * 8)]);
      bf16x8 bv1 = ld8(&Vs[cur][(nt * 16 + l15) * 64 + (((4 + quad) ^ l7) * 8)]);
      o[nt] = __builtin_amdgcn_mfma_f32_16x16x32_bf16(ap0, bv0, o[nt], 0, 0, 0);
      o[nt] = __builtin_amdgcn_mfma_f32_16x16x32_bf16(ap1, bv1, o[nt], 0, 0, 0);
    }
    __builtin_amdgcn_s_setprio(0);
  }

  const float linv = 1.f / l_l;
  float lv[4];
#pragma unroll
  for (int r = 0; r < 4; ++r) lv[r] = __shfl(linv, quad * 4 + r, 64);
  const int qr = bq * 64 + wave * 16 + quad * 4;
#pragma unroll
  for (int nt = 0; nt < 4; ++nt)
#pragma unroll
    for (int r = 0; r < 4; ++r) {
      float v = o[nt][r] * lv[r];
      ctx[(size_t)(b * Sz + qr + r) * Dz + h * DHz + nt * 16 + l15] = f2b(v);
    }
}

// ---------------- layernorm (row = 768) ----------------
__global__ __launch_bounds__(256)
void ln_k(const float* __restrict__ in, const float* __restrict__ g,
          const float* __restrict__ be, float* __restrict__ outF,
          u16* __restrict__ outB) {
  const int row = blockIdx.x;
  const float* x = in + (size_t)row * Dz;
  const int tid = threadIdx.x;
  float v0 = x[tid], v1 = x[tid + 256], v2 = x[tid + 512];
  float s = v0 + v1 + v2;
  float s2 = v0 * v0 + v1 * v1 + v2 * v2;
#pragma unroll
  for (int off = 1; off < 64; off <<= 1) {
    s += __shfl_xor(s, off, 64);
    s2 += __shfl_xor(s2, off, 64);
  }
  __shared__ float red[8];
  int wave = tid >> 6, lane = tid & 63;
  if (lane == 0) { red[wave] = s; red[4 + wave] = s2; }
  __syncthreads();
  s = red[0] + red[1] + red[2] + red[3];
  s2 = red[4] + red[5] + red[6] + red[7];
  const float mu = s * (1.f / 768.f);
  const float rstd = rsqrtf(s2 * (1.f / 768.f) - mu * mu + 1e-5f);
  float vv[3] = {v0, v1, v2};
#pragma unroll
  for (int e = 0; e < 3; ++e) {
    int col = tid + e * 256;
    float y = (vv[e] - mu) * rstd * g[col] + be[col];
    outF[(size_t)row * Dz + col] = y;
    if (outB) outB[(size_t)row * Dz + col] = f2b(y);
  }
}

// ---------------- launch ----------------
extern "C" void kernel_launch(void* const* d_in, const int* in_sizes, int n_in,
                              void* d_out, int out_size, void* d_ws,
                              size_t ws_size, hipStream_t stream) {
  const float* x   = (const float*)d_in[0];
  const int*   msk = (const int*)d_in[1];
  const float* Wq  = (const float*)d_in[2];
  const float* bq  = (const float*)d_in[3];
  const float* Wk  = (const float*)d_in[4];
  const float* bk  = (const float*)d_in[5];
  const float* Wv  = (const float*)d_in[6];
  const float* bv  = (const float*)d_in[7];
  const float* Wo  = (const float*)d_in[8];
  const float* bo  = (const float*)d_in[9];
  const float* g1  = (const float*)d_in[10];
  const float* be1 = (const float*)d_in[11];
  const float* W1  = (const float*)d_in[12];
  const float* b1  = (const float*)d_in[13];
  const float* W2  = (const float*)d_in[14];
  const float* b2  = (const float*)d_in[15];
  const float* g2  = (const float*)d_in[16];
  const float* be2 = (const float*)d_in[17];
  float* out = (float*)d_out;

  char* ws = (char*)d_ws;
  u16*   xb    = (u16*)(ws + 0);
  u16*   wqkvb = (u16*)(ws + 12582912);   // [2304][768] bf16 (transposed)
  u16*   wob   = (u16*)(ws + 16121856);   // [768][768]
  u16*   w1b   = (u16*)(ws + 17301504);   // [1536][768]
  u16*   w2b   = (u16*)(ws + 19660800);   // [768][1536]
  u16*   qb    = (u16*)(ws + 22020096);
  u16*   kb    = (u16*)(ws + 34603008);
  u16*   vtb   = (u16*)(ws + 47185920);
  u16*   ctx   = (u16*)(ws + 59768832);
  float* att   = (float*)(ws + 72351744);
  float* hf    = (float*)(ws + 97517568);
  u16*   hb    = (u16*)(ws + 122683392);
  u16*   f1    = (u16*)(ws + 47185920);  // reuse vt+ctx (dead after O-proj)
  float* yy    = (float*)(ws + 22020096); // reuse q+k (dead after attention)

  cvt4<<<6291456 / 4 / 256, 256, 0, stream>>>(x, xb, 6291456 / 4);
  wtrans<<<dim3(2304 / 32, 768 / 32), 256, 0, stream>>>(Wq, Wk, Wv, wqkvb, 768,
                                                        2304, 768);
  wtrans<<<dim3(24, 24), 256, 0, stream>>>(Wo, nullptr, nullptr, wob, 768, 768,
                                           768);
  wtrans<<<dim3(48, 24), 256, 0, stream>>>(W1, nullptr, nullptr, w1b, 768, 1536,
                                           1536);
  wtrans<<<dim3(24, 48), 256, 0, stream>>>(W2, nullptr, nullptr, w2b, 1536, 768,
                                           768);

  // QKV: [8192x768] @ [768x2304]
  gemm_k<0><<<dim3(2304 / 128, 8192 / 128), 256, 0, stream>>>(
      xb, wqkvb, 8192, 2304, 768, bq, bk, bv, nullptr, nullptr, nullptr, qb, kb,
      vtb);
  // attention
  attn_k<<<dim3(Sz / 64, Bz * Hz), 256, 0, stream>>>(qb, kb, vtb, msk, ctx);
  // O-proj + residual x -> att (fp32)
  gemm_k<1><<<dim3(768 / 128, 8192 / 128), 256, 0, stream>>>(
      ctx, wob, 8192, 768, 768, bo, nullptr, nullptr, x, att, nullptr, nullptr,
      nullptr, nullptr);
  // LN1 -> hf (fp32) + hb (bf16)
  ln_k<<<8192, 256, 0, stream>>>(att, g1, be1, hf, hb);
  // FFN1 + relu -> f1 (bf16)
  gemm_k<2><<<dim3(1536 / 128, 8192 / 128), 256, 0, stream>>>(
      hb, w1b, 8192, 1536, 768, b1, nullptr, nullptr, nullptr, nullptr, f1,
      nullptr, nullptr, nullptr);
  // FFN2 + residual hf -> yy (fp32)
  gemm_k<1><<<dim3(768 / 128, 8192 / 128), 256, 0, stream>>>(
      f1, w2b, 8192, 768, 1536, b2, nullptr, nullptr, hf, yy, nullptr, nullptr,
      nullptr, nullptr);
  // LN2 -> out
  ln_k<<<8192, 256, 0, stream>>>(yy, g2, be2, out, nullptr);
}